// Round 4
// baseline (392.923 us; speedup 1.0000x reference)
//
#include <hip/hip_runtime.h>
#include <math.h>

typedef unsigned short u16;
typedef unsigned int u32;

#define B_   256
#define F_   512
#define T_   81
#define WIN_ 1022
#define HOP_ 400
#define NF_  69
#define OUT_LEN_ 28550
#define SEG_ 1000
#define OVL_ 50

#define MA_  20736     // B_*T_ = 81*256
#define MB_  17664     // B_*NF_ = 69*256
#define K_   1024
#define NBLK0 324      // (MA_/256) * (1024/256)
#define NBLK1 276      // (MB_/256) * (1024/256)

// workspace byte offsets
#define BASA_B     0u                         // 1024*1024 bf16 = 2 MiB
#define BASB_B     (BASA_B + 2097152u)
#define ABUF_B     (BASB_B + 2097152u)        // 20736*1024 bf16
#define TF_B       (ABUF_B + 42467328u)       // 20736*1024 bf16
#define OUTF_B     (TF_B + 42467328u)         // 256*28672 bf16
#define OUTF_STRIDE_ 28672

typedef __attribute__((ext_vector_type(8))) short bf8_t;
typedef __attribute__((ext_vector_type(4))) float f4_t;
typedef const __attribute__((address_space(1))) void* as1cv;
typedef __attribute__((address_space(3))) void* as3v;

__device__ __forceinline__ float b2f(u16 v) {
  u32 u = ((u32)v) << 16; float f; __builtin_memcpy(&f, &u, 4); return f;
}
__device__ __forceinline__ u16 f2b(float f) {
  u32 u; __builtin_memcpy(&u, &f, 4);
  return (u16)((u + 0x7fffu + ((u >> 16) & 1u)) >> 16);
}

// ---------------------------------------------------------------------------
// BasisA[n][2k+j]: iDFT basis, transposed (n-major), synwin/N and c_k folded.
// ---------------------------------------------------------------------------
__global__ __launch_bounds__(256) void gen_basisA(u16* __restrict__ BA) {
  int n = blockIdx.x;                 // 0..1023
  const float twopi_N = 6.283185307179586f / (float)WIN_;
  float scale = 0.f;
  if (n < WIN_) {
    float w = 0.5f - 0.5f * cosf(twopi_N * (float)n);
    int j = n % HOP_;
    float a = 0.5f - 0.5f * cosf(twopi_N * (float)j);
    float b = 0.5f - 0.5f * cosf(twopi_N * (float)(j + 400));
    float d = a * a + b * b;
    if (j + 800 < WIN_) {
      float c2 = 0.5f - 0.5f * cosf(twopi_N * (float)(j + 800));
      d += c2 * c2;
    }
    scale = (w / d) * (1.0f / (float)WIN_);
  }
  for (int k = threadIdx.x; k < 512; k += 256) {
    int m = (k * n) % WIN_;
    float ang = twopi_N * (float)m;
    float s, c; __sincosf(ang, &s, &c);
    bool edge = (k == 0) || (k == 511);
    float ck = edge ? 1.f : 2.f;
    float re = scale * ck * c;
    float im = edge ? 0.f : -scale * ck * s;
    BA[(size_t)n * K_ + 2 * k]     = f2b(re);
    BA[(size_t)n * K_ + 2 * k + 1] = f2b(im);
  }
}

// ---------------------------------------------------------------------------
// BasisB[2k+j][w]: forward DFT basis, transposed, hann folded; 0 for w>=1022.
// ---------------------------------------------------------------------------
__global__ __launch_bounds__(256) void gen_basisB(u16* __restrict__ BB) {
  int k = blockIdx.x;                 // 0..511
  const float twopi_N = 6.283185307179586f / (float)WIN_;
  for (int w = threadIdx.x; w < K_; w += 256) {
    float re = 0.f, im = 0.f;
    if (w < WIN_) {
      int m = (k * w) % WIN_;
      float ang = twopi_N * (float)m;
      float s, c; __sincosf(ang, &s, &c);
      float h = 0.5f - 0.5f * cosf(twopi_N * (float)w);
      re = h * c; im = -h * s;
    }
    BB[(size_t)(2 * k)     * K_ + w] = f2b(re);
    BB[(size_t)(2 * k + 1) * K_ + w] = f2b(im);
  }
}

// ---------------------------------------------------------------------------
// prep1: x[b][k][t][2] fp32 -> Abuf[b*81+t][2k+j] bf16 (LDS-tiled transpose)
// ---------------------------------------------------------------------------
__global__ __launch_bounds__(256) void prep1(const float* __restrict__ x,
                                             u16* __restrict__ Abuf) {
  __shared__ float2 tile[32][33];
  int k0 = blockIdx.x * 32, t0 = blockIdx.y * 32, b = blockIdx.z;
  int c = threadIdx.x & 31, rr = threadIdx.x >> 5;
  const float2* xp = (const float2*)x;
#pragma unroll
  for (int i = 0; i < 4; ++i) {
    int k = k0 + rr + 8 * i, t = t0 + c;
    float2 v = make_float2(0.f, 0.f);
    if (t < T_) v = xp[(size_t)(b * F_ + k) * T_ + t];
    tile[rr + 8 * i][c] = v;
  }
  __syncthreads();
#pragma unroll
  for (int i = 0; i < 4; ++i) {
    int t = t0 + rr + 8 * i, kc = c;
    if (t < T_) {
      float2 v = tile[kc][rr + 8 * i];
      u32 packed = (u32)f2b(v.x) | ((u32)f2b(v.y) << 16);
      *(u32*)&Abuf[(size_t)(b * T_ + t) * K_ + 2 * (k0 + kc)] = packed;
    }
  }
}

// ---------------------------------------------------------------------------
// GEMM: C[M x 1024] = A[M x 1024] * Bt[1024 x 1024]^T  (Bt stored n-major)
//
// 256x256 tile, BK=32, 8 waves (2M x 4N), per-wave 128x64 (acc[8][4]).
// KEY CHANGE vs prev round: B is NOT staged through LDS. Bt is 2 MiB and
// L2-resident under the XCD swizzle; each wave loads its 4 B-fragments
// (global dwordx4) into a register double-buffer one K-step ahead. LDS now
// holds only A: 4 rotating 16-KiB fragment-ordered buffers = 64 KiB ->
// 2 blocks/CU (16 waves). This (a) removes the 1-block/CU grid-quantization
// tail (324/276 blocks all co-resident in 512 slots), (b) halves DS-pipe
// traffic so MFMA is the binding pipe, (c) one barrier per K-step.
//
// Per K-step t:  ds_read a[0..7] (buf t&3); load bnext <- B(t+1) (4 x
// dwordx4); stage A(t+3) (2 x global_load_lds, buf (t-1)&3 whose reads
// finished in step t-1); 32 MFMA (a x bcur); boundary s_waitcnt vmcnt(2)
// [issue order B-then-A => retires B(t+1) fully + A(t+2), keeps A(t+3)
// in flight across the barrier; vmcnt(0) only at t=29,30]; s_barrier.
// Cross-wave A visibility: A(t) stages retired by each stager's boundary
// wait at end of t-2, published by that barrier.
// Grid: m204 bijective XCD swizzle; consecutive wgids share one M-strip.
// EPI 0: A from dense rows (stride K_), store bf16 C.
// EPI 1: A read from outf (row m=b*69+f at b*28672+f*400); LDS repack
//        epilogue (stride-17 f32, 64-row chunks -> <=4-way banks), float2
//        scatter to d_out.
// ---------------------------------------------------------------------------
template <int EPI>
__global__ __launch_bounds__(512, 2) void gemm_bf16(const u16* __restrict__ A,
                                                    const u16* __restrict__ Bt,
                                                    void* __restrict__ Cout) {
  __shared__ u16 sA4[4][8192];   // 4 bufs x 16 frags x 512 u16 = 64 KiB
  const int tid = threadIdx.x;
  const int lane = tid & 63, wv = tid >> 6;   // 8 waves
  const int wm = wv >> 2, wn = wv & 3;        // 2 (M) x 4 (N)
  const int fr = lane & 15, fq = lane >> 4;

  const int nwg = (EPI == 0) ? NBLK0 : NBLK1;
  const int q = nwg >> 3, r = nwg & 7;
  int orig = blockIdx.x;
  int xcd = orig & 7, pos = orig >> 3;
  int wgid = (xcd < r ? xcd * (q + 1) : r * (q + 1) + (xcd - r) * q) + pos;
  const int mt = wgid >> 2, nt = wgid & 3;
  const int bm = mt * 256, bn = nt * 256;

  // A staging source pointers: wave wv stages frags {wv, wv+8}
  const u16 *pA0, *pA1;
  if (EPI == 0) {
    pA0 = A + (size_t)(bm + 16 * wv + fr) * K_ + fq * 8;
    pA1 = A + (size_t)(bm + 16 * (wv + 8) + fr) * K_ + fq * 8;
  } else {
    int m0 = bm + 16 * wv + fr;
    int b0 = m0 / NF_, f0 = m0 - b0 * NF_;
    pA0 = A + (size_t)b0 * OUTF_STRIDE_ + f0 * HOP_ + fq * 8;
    int m1 = m0 + 128;
    int b1 = m1 / NF_, f1 = m1 - b1 * NF_;
    pA1 = A + (size_t)b1 * OUTF_STRIDE_ + f1 * HOP_ + fq * 8;
  }
  // B fragment pointers (register path, L2-hot): lane reads 16 B of row
  // (bn + wn*64 + j*16 + fr) at k-offset fq*8; step offset t*32 u16 = 64 B
  // (fits the 13-bit signed global imm -> single base per j).
  const u16* pB[4];
#pragma unroll
  for (int j = 0; j < 4; ++j)
    pB[j] = Bt + (size_t)(bn + wn * 64 + j * 16 + fr) * K_ + fq * 8;

  f4_t acc[8][4];
#pragma unroll
  for (int i = 0; i < 8; ++i)
#pragma unroll
    for (int j = 0; j < 4; ++j) acc[i][j] = (f4_t){0.f, 0.f, 0.f, 0.f};

  auto STAGE_A = [&](int t) {
    const int buf = t & 3;
    const int ko = t * 32;
    __builtin_amdgcn_global_load_lds((as1cv)(const void*)(pA0 + ko),
                                     (as3v)(&sA4[buf][(wv)     * 512]), 16, 0, 0);
    __builtin_amdgcn_global_load_lds((as1cv)(const void*)(pA1 + ko),
                                     (as3v)(&sA4[buf][(wv + 8) * 512]), 16, 0, 0);
  };

  bf8_t bX[4], bY[4];

  // prologue: B(0) regs first, then A(0..2); vmcnt(4) retires B0+A0,
  // leaves A1,A2 in flight.
#pragma unroll
  for (int j = 0; j < 4; ++j) bX[j] = *(const bf8_t*)&pB[j][0];
  STAGE_A(0); STAGE_A(1); STAGE_A(2);
  asm volatile("s_waitcnt vmcnt(4)" ::: "memory");
  __builtin_amdgcn_s_barrier();

  auto STEP = [&](int t, bf8_t (&bc)[4], bf8_t (&bnx)[4]) {
    const u16* sAc = &sA4[t & 3][0];
    bf8_t a[8];
#pragma unroll
    for (int i = 0; i < 8; ++i)
      a[i] = *(const bf8_t*)&sAc[(wm * 8 + i) * 512 + lane * 8];
    if (t + 1 < 32) {
#pragma unroll
      for (int j = 0; j < 4; ++j)
        bnx[j] = *(const bf8_t*)&pB[j][(t + 1) * 32];
    }
    if (t + 3 < 32) STAGE_A(t + 3);   // buf (t-1)&3: reads done in step t-1
    __builtin_amdgcn_s_setprio(1);
#pragma unroll
    for (int i = 0; i < 8; ++i)
#pragma unroll
      for (int j = 0; j < 4; ++j)
        acc[i][j] = __builtin_amdgcn_mfma_f32_16x16x32_bf16(a[i], bc[j], acc[i][j], 0, 0, 0);
    __builtin_amdgcn_s_setprio(0);
    // boundary: retire B(t+1) + A(t+2); keep A(t+3) in flight
    if (t <= 28)      asm volatile("s_waitcnt vmcnt(2)" ::: "memory");
    else if (t <= 30) asm volatile("s_waitcnt vmcnt(0)" ::: "memory");
    if (t < 31) __builtin_amdgcn_s_barrier();
  };

  for (int tt = 0; tt < 16; ++tt) {
    STEP(2 * tt,     bX, bY);
    STEP(2 * tt + 1, bY, bX);
  }

  if (EPI == 0) {
    u16* C = (u16*)Cout;
#pragma unroll
    for (int i = 0; i < 8; ++i)
#pragma unroll
      for (int j = 0; j < 4; ++j) {
        int colg = bn + wn * 64 + 16 * j + fr;
#pragma unroll
        for (int rr2 = 0; rr2 < 4; ++rr2) {
          int rowg = bm + wm * 128 + 16 * i + fq * 4 + rr2;
          C[(size_t)rowg * K_ + colg] = f2b(acc[i][j][rr2]);
        }
      }
  } else {
    // per-wave LDS repack (stride-17 f32, 64-row chunks) -> float2 scatter
    // into out[b][k][f][2]. Region: wv*1088 floats (4352 B) -> 34816 B total.
    __builtin_amdgcn_s_barrier();       // all waves past step 31 reads
    float* out = (float*)Cout;
    float* ep = (float*)&sA4[0][0] + (size_t)wv * 1088;
    for (int j = 0; j < 4; ++j) {
      for (int rh = 0; rh < 2; ++rh) {
#pragma unroll
        for (int i2 = 0; i2 < 4; ++i2)
#pragma unroll
          for (int rr2 = 0; rr2 < 4; ++rr2)
            ep[(16 * i2 + fq * 4 + rr2) * 17 + fr] = acc[rh * 4 + i2][j][rr2];
        asm volatile("s_waitcnt lgkmcnt(0)" ::: "memory");  // writes done
        int m = bm + wm * 128 + rh * 64 + lane;
        int bb = m / NF_, ff = m - bb * NF_;
        int colbase = bn + wn * 64 + 16 * j;  // even
#pragma unroll
        for (int a2 = 0; a2 < 8; ++a2) {
          int k = (colbase >> 1) + a2;
          float2 v = make_float2(ep[lane * 17 + 2 * a2], ep[lane * 17 + 2 * a2 + 1]);
          ((float2*)out)[((size_t)bb * F_ + k) * NF_ + ff] = v;
        }
        asm volatile("s_waitcnt lgkmcnt(0)" ::: "memory");  // reads before WAR
      }
    }
  }
}

// ---------------------------------------------------------------------------
// fold: overlap-add gather + keep + crossfade (bf16 in / bf16 out)
// ---------------------------------------------------------------------------
__device__ __forceinline__ float sigval(const u16* __restrict__ tfb, int i) {
  int t1 = i / HOP_; if (t1 > T_ - 1) t1 = T_ - 1;
  int t0 = (i >= WIN_) ? (i - (WIN_ - 1) + HOP_ - 1) / HOP_ : 0;
  float acc = 0.f;
  for (int t = t0; t <= t1; ++t)
    acc += b2f(tfb[(size_t)t * K_ + (i - t * HOP_)]);
  return acc;
}

__global__ __launch_bounds__(256) void k3_fold(const u16* __restrict__ tf,
                                               u16* __restrict__ outf) {
  int id = blockIdx.x * 256 + threadIdx.x;
  if (id >= B_ * OUT_LEN_) return;
  int b = id / OUT_LEN_;
  int p = id - b * OUT_LEN_;
  int s, r;
  if (p < SEG_) { s = 0; r = p; }
  else {
    int q = p - SEG_;
    s = q / (SEG_ - OVL_) + 1;
    r = OVL_ + (q - (s - 1) * (SEG_ - OVL_));
  }
  const u16* tfb = tf + (size_t)b * T_ * K_;
  float val;
  if (r >= SEG_ - OVL_ && s <= 28) {
    float dec = (float)(SEG_ - r) * (1.f / (float)OVL_);
    float inc = (float)(r - (SEG_ - OVL_ - 1)) * (1.f / (float)OVL_);
    float v1 = sigval(tfb, s * 1100 + r);
    float v2 = sigval(tfb, (s + 1) * 1100 + (r - (SEG_ - OVL_)));
    val = dec * v1 + inc * v2;
  } else {
    val = sigval(tfb, s * 1100 + r);
  }
  outf[(size_t)b * OUTF_STRIDE_ + p] = f2b(val);
}

// ---------------------------------------------------------------------------
extern "C" void kernel_launch(void* const* d_in, const int* in_sizes, int n_in,
                              void* d_out, int out_size, void* d_ws, size_t ws_size,
                              hipStream_t stream) {
  const float* x = (const float*)d_in[0];
  char* ws = (char*)d_ws;
  u16* BA   = (u16*)(ws + BASA_B);
  u16* BB   = (u16*)(ws + BASB_B);
  u16* Abuf = (u16*)(ws + ABUF_B);
  u16* TF   = (u16*)(ws + TF_B);
  u16* outf = (u16*)(ws + OUTF_B);

  hipLaunchKernelGGL(gen_basisA, dim3(1024), dim3(256), 0, stream, BA);
  hipLaunchKernelGGL(gen_basisB, dim3(512), dim3(256), 0, stream, BB);
  hipLaunchKernelGGL(prep1, dim3(16, 3, 256), dim3(256), 0, stream, x, Abuf);
  hipLaunchKernelGGL((gemm_bf16<0>), dim3(NBLK0), dim3(512), 0, stream,
                     Abuf, BA, (void*)TF);
  int n3 = B_ * OUT_LEN_;
  hipLaunchKernelGGL(k3_fold, dim3((n3 + 255) / 256), dim3(256), 0, stream, TF, outf);
  hipLaunchKernelGGL((gemm_bf16<1>), dim3(NBLK1), dim3(512), 0, stream,
                     outf, BB, (void*)d_out);
}

// Round 6
// 314.750 us; speedup vs baseline: 1.2484x; 1.2484x over previous
//
#include <hip/hip_runtime.h>
#include <math.h>

typedef unsigned short u16;
typedef unsigned int u32;

#define B_   256
#define F_   512
#define T_   81
#define WIN_ 1022
#define HOP_ 400
#define NF_  69
#define OUT_LEN_ 28550
#define SEG_ 1000
#define OVL_ 50

#define MA_  20736     // B_*T_ = 81*256
#define MB_  17664     // B_*NF_ = 69*256
#define K_   1024
#define NBLK0 324      // (MA_/256) * (1024/256)
#define NBLK1 276      // (MB_/256) * (1024/256)

// workspace byte offsets
#define BASA_B     0u                         // 1024*1024 bf16 = 2 MiB
#define BASB_B     (BASA_B + 2097152u)
#define ABUF_B     (BASB_B + 2097152u)        // 20736*1024 bf16
#define TF_B       (ABUF_B + 42467328u)       // 20736*1024 bf16
#define OUTF_B     (TF_B + 42467328u)         // 256*28672 bf16
#define OUTF_STRIDE_ 28672

typedef __attribute__((ext_vector_type(8))) short bf8_t;
typedef __attribute__((ext_vector_type(4))) float f4_t;
typedef const __attribute__((address_space(1))) void* as1cv;
typedef __attribute__((address_space(3))) void* as3v;

__device__ __forceinline__ float b2f(u16 v) {
  u32 u = ((u32)v) << 16; float f; __builtin_memcpy(&f, &u, 4); return f;
}
__device__ __forceinline__ u16 f2b(float f) {
  u32 u; __builtin_memcpy(&u, &f, 4);
  return (u16)((u + 0x7fffu + ((u >> 16) & 1u)) >> 16);
}

// ---------------------------------------------------------------------------
// Fused basis generation. Blocks 0..1023: BasisA[n][2k+j] (iDFT, transposed,
// synwin/N + c_k folded). Blocks 1024..1535: BasisB[2k+j][w] (fwd DFT,
// transposed, hann folded; 0 for w>=1022).
// ---------------------------------------------------------------------------
__global__ __launch_bounds__(256) void gen_basis(u16* __restrict__ BA,
                                                 u16* __restrict__ BB) {
  const float twopi_N = 6.283185307179586f / (float)WIN_;
  int bid = blockIdx.x;
  if (bid < 1024) {
    int n = bid;                      // 0..1023
    float scale = 0.f;
    if (n < WIN_) {
      float w = 0.5f - 0.5f * cosf(twopi_N * (float)n);
      int j = n % HOP_;
      float a = 0.5f - 0.5f * cosf(twopi_N * (float)j);
      float b = 0.5f - 0.5f * cosf(twopi_N * (float)(j + 400));
      float d = a * a + b * b;
      if (j + 800 < WIN_) {
        float c2 = 0.5f - 0.5f * cosf(twopi_N * (float)(j + 800));
        d += c2 * c2;
      }
      scale = (w / d) * (1.0f / (float)WIN_);
    }
    for (int k = threadIdx.x; k < 512; k += 256) {
      int m = (k * n) % WIN_;
      float ang = twopi_N * (float)m;
      float s, c; __sincosf(ang, &s, &c);
      bool edge = (k == 0) || (k == 511);
      float ck = edge ? 1.f : 2.f;
      float re = scale * ck * c;
      float im = edge ? 0.f : -scale * ck * s;
      BA[(size_t)n * K_ + 2 * k]     = f2b(re);
      BA[(size_t)n * K_ + 2 * k + 1] = f2b(im);
    }
  } else {
    int k = bid - 1024;               // 0..511
    for (int w = threadIdx.x; w < K_; w += 256) {
      float re = 0.f, im = 0.f;
      if (w < WIN_) {
        int m = (k * w) % WIN_;
        float ang = twopi_N * (float)m;
        float s, c; __sincosf(ang, &s, &c);
        float h = 0.5f - 0.5f * cosf(twopi_N * (float)w);
        re = h * c; im = -h * s;
      }
      BB[(size_t)(2 * k)     * K_ + w] = f2b(re);
      BB[(size_t)(2 * k + 1) * K_ + w] = f2b(im);
    }
  }
}

// ---------------------------------------------------------------------------
// prep1: x[b][k][t][2] fp32 -> Abuf[b*81+t][2k+j] bf16 (LDS-tiled transpose)
// ---------------------------------------------------------------------------
__global__ __launch_bounds__(256) void prep1(const float* __restrict__ x,
                                             u16* __restrict__ Abuf) {
  __shared__ float2 tile[32][33];
  int k0 = blockIdx.x * 32, t0 = blockIdx.y * 32, b = blockIdx.z;
  int c = threadIdx.x & 31, rr = threadIdx.x >> 5;
  const float2* xp = (const float2*)x;
#pragma unroll
  for (int i = 0; i < 4; ++i) {
    int k = k0 + rr + 8 * i, t = t0 + c;
    float2 v = make_float2(0.f, 0.f);
    if (t < T_) v = xp[(size_t)(b * F_ + k) * T_ + t];
    tile[rr + 8 * i][c] = v;
  }
  __syncthreads();
#pragma unroll
  for (int i = 0; i < 4; ++i) {
    int t = t0 + rr + 8 * i, kc = c;
    if (t < T_) {
      float2 v = tile[kc][rr + 8 * i];
      u32 packed = (u32)f2b(v.x) | ((u32)f2b(v.y) << 16);
      *(u32*)&Abuf[(size_t)(b * T_ + t) * K_ + 2 * (k0 + kc)] = packed;
    }
  }
}

// ---------------------------------------------------------------------------
// GEMM: C[M x 1024] = A[M x 1024] * Bt[1024 x 1024]^T  (Bt stored n-major)
//
// 256x256 tile, BK=32, 8 waves (2M x 4N), per-wave 128x64 (acc[8][4]).
// LDS: 4 rotating 32-KiB buffers (A 16 KiB + B 16 KiB), fragment-ordered
// (lane l's 16 B at byte l*16 of each 1-KiB frag): gload_lds dest linear,
// ds_read_b128 sequential -> 0 bank conflicts.
//
// SCHEDULE: ONE phase per K-step with register double-buffering (X/Y frag
// sets). Iter t:
//   issue 12 ds_read[t+1] -> NXT regs   (tile t+1 retired at boundary t-1)
//   issue STAGE(t+3) (4 gload_lds; buf (t-1)&3, whose reads all completed
//     before barrier(t-1) in every wave, so no WAR)
//   setprio(1); 32 MFMA on CUR regs (compiler places the counted lgkm wait
//     for CUR's reads, issued one iter ago -> DS latency hidden); setprio(0)
//   boundary: vmcnt(4) retires stage(t+2), leaves stage(t+3) IN FLIGHT
//     across the barrier (vmcnt(0) only at t=29); ONE s_barrier per K-step.
// vmcnt ledger: prologue 12 issued, vmcnt(4) -> tiles 0,1 resident; steady
// boundary of iter s retires stage(s+2) => LOADF(t+1) at iter t targets a
// tile retired one barrier earlier. Last STAGE(31) at t=28 retired by
// vmcnt(0) at t=29; nothing outstanding at the epilogue.
// Grid: m204 bijective XCD swizzle; consecutive wgids share one M-strip.
// EPI 0: A from dense rows (stride K_), store bf16 C.
// EPI 1: A read from outf (row m=b*69+f at b*28672+f*400); stride-17 LDS
//        repack epilogue, float2 scatter to d_out.
// ---------------------------------------------------------------------------
template <int EPI>
__global__ __launch_bounds__(512, 2) void gemm_bf16(const u16* __restrict__ A,
                                                    const u16* __restrict__ Bt,
                                                    void* __restrict__ Cout) {
  __shared__ u16 sAB[4][16384];   // [buf]: A frags @0, B frags @8192 (u16 units)
  const int tid = threadIdx.x;
  const int lane = tid & 63, wv = tid >> 6;   // 8 waves
  const int wm = wv >> 2, wn = wv & 3;        // 2 (M) x 4 (N)
  const int fr = lane & 15, fq = lane >> 4;

  const int nwg = (EPI == 0) ? NBLK0 : NBLK1;
  const int q = nwg >> 3, r = nwg & 7;
  int orig = blockIdx.x;
  int xcd = orig & 7, pos = orig >> 3;
  int wgid = (xcd < r ? xcd * (q + 1) : r * (q + 1) + (xcd - r) * q) + pos;
  const int mt = wgid >> 2, nt = wgid & 3;
  const int bm = mt * 256, bn = nt * 256;

  // staging source pointers: wave wv stages A-frags {wv, wv+8}, B-frags {wv, wv+8}
  const u16 *pA0, *pA1;
  if (EPI == 0) {
    pA0 = A + (size_t)(bm + 16 * wv + fr) * K_ + fq * 8;
    pA1 = A + (size_t)(bm + 16 * (wv + 8) + fr) * K_ + fq * 8;
  } else {
    int m0 = bm + 16 * wv + fr;
    int b0 = m0 / NF_, f0 = m0 - b0 * NF_;
    pA0 = A + (size_t)b0 * OUTF_STRIDE_ + f0 * HOP_ + fq * 8;
    int m1 = m0 + 128;
    int b1 = m1 / NF_, f1 = m1 - b1 * NF_;
    pA1 = A + (size_t)b1 * OUTF_STRIDE_ + f1 * HOP_ + fq * 8;
  }
  const u16* pB0 = Bt + (size_t)(bn + 16 * wv + fr) * K_ + fq * 8;
  const u16* pB1 = Bt + (size_t)(bn + 16 * (wv + 8) + fr) * K_ + fq * 8;

  f4_t acc[8][4];
#pragma unroll
  for (int i = 0; i < 8; ++i)
#pragma unroll
    for (int j = 0; j < 4; ++j) acc[i][j] = (f4_t){0.f, 0.f, 0.f, 0.f};

  auto STAGE = [&](int t) {
    const int buf = t & 3;
    const int ko = t * 32;
    __builtin_amdgcn_global_load_lds((as1cv)(const void*)(pA0 + ko),
                                     (as3v)(&sAB[buf][(wv)     * 512]), 16, 0, 0);
    __builtin_amdgcn_global_load_lds((as1cv)(const void*)(pA1 + ko),
                                     (as3v)(&sAB[buf][(wv + 8) * 512]), 16, 0, 0);
    __builtin_amdgcn_global_load_lds((as1cv)(const void*)(pB0 + ko),
                                     (as3v)(&sAB[buf][8192 + (wv)     * 512]), 16, 0, 0);
    __builtin_amdgcn_global_load_lds((as1cv)(const void*)(pB1 + ko),
                                     (as3v)(&sAB[buf][8192 + (wv + 8) * 512]), 16, 0, 0);
  };

  auto LOADF = [&](int t, bf8_t (&a)[8], bf8_t (&b)[4]) {
    const u16* sA = &sAB[t & 3][0];
    const u16* sB = &sAB[t & 3][8192];
#pragma unroll
    for (int i = 0; i < 8; ++i)
      a[i] = *(const bf8_t*)&sA[(wm * 8 + i) * 512 + lane * 8];
#pragma unroll
    for (int j = 0; j < 4; ++j)
      b[j] = *(const bf8_t*)&sB[(wn * 4 + j) * 512 + lane * 8];
  };

  bf8_t aX[8], bX[4], aY[8], bY[4];

  // prologue: stage tiles 0,1,2 (12 loads); vmcnt(4) retires tiles 0,1
  // (tile 2 stays in flight); read tile 0 frags into X.
  STAGE(0); STAGE(1); STAGE(2);
  asm volatile("s_waitcnt vmcnt(4)" ::: "memory");
  __builtin_amdgcn_s_barrier();
  LOADF(0, aX, bX);

#define ITER(t, aC, bC, aN, bN)                                              \
  {                                                                          \
    if ((t) + 1 < 32) LOADF((t) + 1, aN, bN);                                \
    if ((t) + 3 < 32) STAGE((t) + 3);                                        \
    __builtin_amdgcn_s_setprio(1);                                           \
    _Pragma("unroll") for (int i = 0; i < 8; ++i)                            \
      _Pragma("unroll") for (int j = 0; j < 4; ++j)                          \
        acc[i][j] = __builtin_amdgcn_mfma_f32_16x16x32_bf16(aC[i], bC[j],    \
                                                            acc[i][j], 0, 0, 0); \
    __builtin_amdgcn_s_setprio(0);                                           \
    if ((t) <= 28)      asm volatile("s_waitcnt vmcnt(4)" ::: "memory");     \
    else if ((t) == 29) asm volatile("s_waitcnt vmcnt(0)" ::: "memory");     \
    if ((t) < 31) __builtin_amdgcn_s_barrier();                              \
  }

  for (int tt = 0; tt < 16; ++tt) {
    ITER(2 * tt,     aX, bX, aY, bY);
    ITER(2 * tt + 1, aY, bY, aX, bX);
  }
#undef ITER

  if (EPI == 0) {
    u16* C = (u16*)Cout;
#pragma unroll
    for (int i = 0; i < 8; ++i)
#pragma unroll
      for (int j = 0; j < 4; ++j) {
        int colg = bn + wn * 64 + 16 * j + fr;
#pragma unroll
        for (int rr2 = 0; rr2 < 4; ++rr2) {
          int rowg = bm + wm * 128 + 16 * i + fq * 4 + rr2;
          C[(size_t)rowg * K_ + colg] = f2b(acc[i][j][rr2]);
        }
      }
  } else {
    // per-wave LDS repack (stride-17 f32, 64-row chunks) -> float2 scatter
    // into out[b][k][f][2]. Repack region bufs 0-1 (wv*4352 B): tiles 28/29,
    // whose reads finished before barrier(30) which every wave has crossed.
    __builtin_amdgcn_s_barrier();
    float* out = (float*)Cout;
    float* ep = (float*)&sAB[0][0] + (size_t)wv * 1088;
    for (int j = 0; j < 4; ++j) {
      for (int rh = 0; rh < 2; ++rh) {
#pragma unroll
        for (int i2 = 0; i2 < 4; ++i2)
#pragma unroll
          for (int rr2 = 0; rr2 < 4; ++rr2)
            ep[(16 * i2 + fq * 4 + rr2) * 17 + fr] = acc[rh * 4 + i2][j][rr2];
        asm volatile("s_waitcnt lgkmcnt(0)" ::: "memory");  // writes done
        int m = bm + wm * 128 + rh * 64 + lane;
        int bb = m / NF_, ff = m - bb * NF_;
        int colbase = bn + wn * 64 + 16 * j;  // even
#pragma unroll
        for (int a2 = 0; a2 < 8; ++a2) {
          int k = (colbase >> 1) + a2;
          float2 v = make_float2(ep[lane * 17 + 2 * a2], ep[lane * 17 + 2 * a2 + 1]);
          ((float2*)out)[((size_t)bb * F_ + k) * NF_ + ff] = v;
        }
        asm volatile("s_waitcnt lgkmcnt(0)" ::: "memory");  // reads before WAR
      }
    }
  }
}

// ---------------------------------------------------------------------------
// fold: overlap-add gather + keep + crossfade (bf16 in / bf16 out)
// ---------------------------------------------------------------------------
__device__ __forceinline__ float sigval(const u16* __restrict__ tfb, int i) {
  int t1 = i / HOP_; if (t1 > T_ - 1) t1 = T_ - 1;
  int t0 = (i >= WIN_) ? (i - (WIN_ - 1) + HOP_ - 1) / HOP_ : 0;
  float acc = 0.f;
  for (int t = t0; t <= t1; ++t)
    acc += b2f(tfb[(size_t)t * K_ + (i - t * HOP_)]);
  return acc;
}

__global__ __launch_bounds__(256) void k3_fold(const u16* __restrict__ tf,
                                               u16* __restrict__ outf) {
  int id = blockIdx.x * 256 + threadIdx.x;
  if (id >= B_ * OUT_LEN_) return;
  int b = id / OUT_LEN_;
  int p = id - b * OUT_LEN_;
  int s, r;
  if (p < SEG_) { s = 0; r = p; }
  else {
    int q = p - SEG_;
    s = q / (SEG_ - OVL_) + 1;
    r = OVL_ + (q - (s - 1) * (SEG_ - OVL_));
  }
  const u16* tfb = tf + (size_t)b * T_ * K_;
  float val;
  if (r >= SEG_ - OVL_ && s <= 28) {
    float dec = (float)(SEG_ - r) * (1.f / (float)OVL_);
    float inc = (float)(r - (SEG_ - OVL_ - 1)) * (1.f / (float)OVL_);
    float v1 = sigval(tfb, s * 1100 + r);
    float v2 = sigval(tfb, (s + 1) * 1100 + (r - (SEG_ - OVL_)));
    val = dec * v1 + inc * v2;
  } else {
    val = sigval(tfb, s * 1100 + r);
  }
  outf[(size_t)b * OUTF_STRIDE_ + p] = f2b(val);
}

// ---------------------------------------------------------------------------
extern "C" void kernel_launch(void* const* d_in, const int* in_sizes, int n_in,
                              void* d_out, int out_size, void* d_ws, size_t ws_size,
                              hipStream_t stream) {
  const float* x = (const float*)d_in[0];
  char* ws = (char*)d_ws;
  u16* BA   = (u16*)(ws + BASA_B);
  u16* BB   = (u16*)(ws + BASB_B);
  u16* Abuf = (u16*)(ws + ABUF_B);
  u16* TF   = (u16*)(ws + TF_B);
  u16* outf = (u16*)(ws + OUTF_B);

  hipLaunchKernelGGL(gen_basis, dim3(1536), dim3(256), 0, stream, BA, BB);
  hipLaunchKernelGGL(prep1, dim3(16, 3, 256), dim3(256), 0, stream, x, Abuf);
  hipLaunchKernelGGL((gemm_bf16<0>), dim3(NBLK0), dim3(512), 0, stream,
                     Abuf, BA, (void*)TF);
  int n3 = B_ * OUT_LEN_;
  hipLaunchKernelGGL(k3_fold, dim3((n3 + 255) / 256), dim3(256), 0, stream, TF, outf);
  hipLaunchKernelGGL((gemm_bf16<1>), dim3(NBLK1), dim3(512), 0, stream,
                     outf, BB, (void*)d_out);
}